// Round 3
// baseline (688.741 us; speedup 1.0000x reference)
//
#include <hip/hip_runtime.h>
#include <stdint.h>

// D = 128 fixed by the problem.
#define FD 128

typedef __bf16 bf16x8 __attribute__((ext_vector_type(8)));
typedef unsigned short u16x8 __attribute__((ext_vector_type(8)));
typedef float  f32x16 __attribute__((ext_vector_type(16)));

__device__ __forceinline__ unsigned short f2bf(float f) {
    unsigned u = __float_as_uint(f);
    unsigned r = u + 0x7fffu + ((u >> 16) & 1u);   // RNE
    return (unsigned short)(r >> 16);
}
__device__ __forceinline__ float bflo(unsigned u) { return __uint_as_float(u << 16); }
__device__ __forceinline__ float bfhi(unsigned u) { return __uint_as_float(u & 0xffff0000u); }

// ---------------------------------------------------------------------------
// prep: weights -> Wf, bf16 in MFMA B-fragment order:
//   Wf[((ct*8 + kt)*64 + lane)*8 + j] = W'[k = kt*16 + (lane>>5)*8 + j]
//                                         [c = ct*32 + (lane&31)]
// where W' = [Wg1 | Wg2 | Ws | Wr] (128 x 512). 512*128 elements = 128 KB.
// ---------------------------------------------------------------------------
__global__ __launch_bounds__(256) void prep_kernel(
    const float* __restrict__ Wg,
    const float* __restrict__ Ws,
    const float* __restrict__ Wr,
    unsigned short* __restrict__ Wf)
{
    int wid = blockIdx.x * 256 + threadIdx.x;      // 0 .. 65535
    if (wid >= 512 * 128) return;
    int j  = wid & 7;
    int l  = (wid >> 3) & 63;
    int kt = (wid >> 9) & 7;
    int ct = wid >> 12;                        // 0..15
    int k  = kt * 16 + (l >> 5) * 8 + j;       // 0..127
    int c  = ct * 32 + (l & 31);               // 0..511
    float v;
    if (c < 128)      v = Wg[k * FD + c];                    // Wg1
    else if (c < 256) v = Wg[(128 + k) * FD + (c - 128)];    // Wg2
    else if (c < 384) v = Ws[k * FD + (c - 256)];            // Ws
    else              v = Wr[k * FD + (c - 384)];            // Wr
    Wf[wid] = f2bf(v);
}

// ---------------------------------------------------------------------------
// gemm: [A|B|S|R] = h @ [Wg1|Wg2|Ws|Wr]  (N x 512 output, K = 128)
// cols 0-127 -> A(+bg, bf16), 128-255 -> B(bf16), 256-383 -> S(+bs, bf16),
// 384-511 -> out(+br, fp32).
// Block = 256 thr = 4 waves; wave w owns weight matrix w (128 cols = 4 tiles
// of 32). 32 rows per block. A operand read fp32 from h, cvt in-register;
// B-frags fully coalesced from pre-swizzled Wf (L2-resident, 128 KB).
// ---------------------------------------------------------------------------
__global__ __launch_bounds__(256) void gemm_kernel(
    const float* __restrict__ h,
    const unsigned short* __restrict__ Wf,
    const float* __restrict__ bg,
    const float* __restrict__ bs,
    const float* __restrict__ br,
    unsigned short* __restrict__ A,
    unsigned short* __restrict__ B,
    unsigned short* __restrict__ S,
    float* __restrict__ out,
    int N)
{
    const int w    = threadIdx.x >> 6;    // 0..3: which weight matrix
    const int lane = threadIdx.x & 63;
    const int rb   = blockIdx.x * 32;

    f32x16 acc[4];
    #pragma unroll
    for (int i = 0; i < 4; ++i)
        #pragma unroll
        for (int r = 0; r < 16; ++r) acc[i][r] = 0.0f;

    int arow = rb + (lane & 31);
    if (arow >= N) arow = N - 1;          // clamp tail rows (dup work, correct out)
    const float* aptr = h + (size_t)arow * FD + (lane >> 5) * 8;

    #pragma unroll
    for (int kt = 0; kt < 8; ++kt) {
        float4 f0 = *(const float4*)(aptr + kt * 16);
        float4 f1 = *(const float4*)(aptr + kt * 16 + 4);
        union { u16x8 u; bf16x8 b; } cv;
        cv.u[0] = f2bf(f0.x); cv.u[1] = f2bf(f0.y);
        cv.u[2] = f2bf(f0.z); cv.u[3] = f2bf(f0.w);
        cv.u[4] = f2bf(f1.x); cv.u[5] = f2bf(f1.y);
        cv.u[6] = f2bf(f1.z); cv.u[7] = f2bf(f1.w);
        bf16x8 a = cv.b;
        #pragma unroll
        for (int i = 0; i < 4; ++i) {
            const unsigned short* bp = Wf + (size_t)(((w * 4 + i) * 8 + kt) * 64 + lane) * 8;
            bf16x8 bfr = *(const bf16x8*)bp;
            acc[i] = __builtin_amdgcn_mfma_f32_32x32x16_bf16(a, bfr, acc[i], 0, 0, 0);
        }
    }

    // C/D layout: col = lane&31, row = (reg&3) + 8*(reg>>2) + 4*(lane>>5)
    const int col_l  = lane & 31;
    const int rhalf  = (lane >> 5) * 4;
    #pragma unroll
    for (int i = 0; i < 4; ++i) {
        int col = i * 32 + col_l;         // 0..127 within this weight matrix
        float bias = (w == 0) ? bg[col] : (w == 2) ? bs[col] : (w == 3) ? br[col] : 0.0f;
        #pragma unroll
        for (int r = 0; r < 16; ++r) {
            int row = rb + (r & 3) + 8 * (r >> 2) + rhalf;
            if (row < N) {
                float v = acc[i][r] + bias;
                size_t off = (size_t)row * FD + col;
                if (w == 0)      A[off] = f2bf(v);    // gate-rec term (+bg folded)
                else if (w == 1) B[off] = f2bf(v);    // gate-send term
                else if (w == 2) S[off] = f2bf(v);    // message content (+bs)
                else             out[off] = v;        // self term h@Wr+br (fp32)
            }
        }
    }
}

// ---------------------------------------------------------------------------
// edge: one wave per edge; lane handles feature pair (2*lane, 2*lane+1).
// eta = sigmoid(A[rec] + B[send]); out[rec] += eta * S[send] (fp32 atomics).
// NOTE: harness passes integer inputs as int32 (NOT the reference's int64).
// ---------------------------------------------------------------------------
__global__ __launch_bounds__(256) void edge_kernel(
    const int* __restrict__ idx,          // [2][E] int32 (harness-converted)
    const unsigned* __restrict__ A,       // bf16x2 per uint, [N][64]
    const unsigned* __restrict__ B,
    const unsigned* __restrict__ S,
    float* __restrict__ out,
    int E)
{
    int e = blockIdx.x * 4 + (threadIdx.x >> 6);
    if (e >= E) return;
    int lane = threadIdx.x & 63;
    int s = idx[e];          // send
    int r = idx[E + e];      // rec

    unsigned ua = A[(size_t)r * 64 + lane];
    unsigned ub = B[(size_t)s * 64 + lane];
    unsigned us = S[(size_t)s * 64 + lane];

    float g0 = bflo(ua) + bflo(ub);
    float g1 = bfhi(ua) + bfhi(ub);
    float e0 = 1.0f / (1.0f + __expf(-g0));
    float e1 = 1.0f / (1.0f + __expf(-g1));
    float m0 = e0 * bflo(us);
    float m1 = e1 * bfhi(us);

    float* o = out + (size_t)r * FD + 2 * lane;
    unsafeAtomicAdd(o,     m0);
    unsafeAtomicAdd(o + 1, m1);
}

// ---------------------------------------------------------------------------
extern "C" void kernel_launch(void* const* d_in, const int* in_sizes, int n_in,
                              void* d_out, int out_size, void* d_ws, size_t ws_size,
                              hipStream_t stream)
{
    const float* h  = (const float*)d_in[0];
    const int*   ei = (const int*)d_in[1];      // int32 per harness contract
    const float* Wg = (const float*)d_in[2];
    const float* bg = (const float*)d_in[3];
    const float* Ws = (const float*)d_in[4];
    const float* bs = (const float*)d_in[5];
    const float* Wr = (const float*)d_in[6];
    const float* br = (const float*)d_in[7];
    float* out = (float*)d_out;

    const int N = in_sizes[0] / FD;       // 100000
    const int E = in_sizes[1] / 2;        // 600000

    // Workspace layout (bf16 = ushort), small first:
    //   Wf [512*128] (128 KB) | A [N*128] | B [N*128] | S [N*128]
    // total = 131072 + 3 * N*128*2 bytes  (= 76.93 MB at N=100000)
    size_t need = 131072 + 3ull * N * FD * 2;
    if (ws_size < need) return;   // diagnostic: absmax will equal memset-0 baseline

    unsigned short* Wf  = (unsigned short*)d_ws;
    unsigned short* Abf = Wf + 512 * FD;
    unsigned short* Bbf = Abf + (size_t)N * FD;
    unsigned short* Sbf = Bbf + (size_t)N * FD;

    prep_kernel<<<(512 * FD + 255) / 256, 256, 0, stream>>>(Wg, Ws, Wr, Wf);
    gemm_kernel<<<(N + 31) / 32, 256, 0, stream>>>(h, Wf, bg, bs, br,
                                                   Abf, Bbf, Sbf, out, N);
    edge_kernel<<<(E + 3) / 4, 256, 0, stream>>>(ei, (const unsigned*)Abf,
                                                 (const unsigned*)Bbf, (const unsigned*)Sbf,
                                                 out, E);
}

// Round 4
// 334.731 us; speedup vs baseline: 2.0576x; 2.0576x over previous
//
#include <hip/hip_runtime.h>
#include <stdint.h>

// D = 128 fixed by the problem.
#define FD 128

typedef __bf16 bf16x8 __attribute__((ext_vector_type(8)));
typedef unsigned short u16x8 __attribute__((ext_vector_type(8)));
typedef float  f32x16 __attribute__((ext_vector_type(16)));

__device__ __forceinline__ unsigned short f2bf(float f) {
    unsigned u = __float_as_uint(f);
    unsigned r = u + 0x7fffu + ((u >> 16) & 1u);   // RNE
    return (unsigned short)(r >> 16);
}
__device__ __forceinline__ float bflo(unsigned u) { return __uint_as_float(u << 16); }
__device__ __forceinline__ float bfhi(unsigned u) { return __uint_as_float(u & 0xffff0000u); }

// ---------------------------------------------------------------------------
// prep: weights -> Wf, bf16 in MFMA B-fragment order:
//   Wf[((ct*8 + kt)*64 + lane)*8 + j] = W'[k = kt*16 + (lane>>5)*8 + j]
//                                         [c = ct*32 + (lane&31)]
// where W' = [Wg1 | Wg2 | Ws | Wr] (128 x 512). 512*128 elements = 128 KB.
// ---------------------------------------------------------------------------
__global__ __launch_bounds__(256) void prep_kernel(
    const float* __restrict__ Wg,
    const float* __restrict__ Ws,
    const float* __restrict__ Wr,
    unsigned short* __restrict__ Wf)
{
    int wid = blockIdx.x * 256 + threadIdx.x;      // 0 .. 65535
    if (wid >= 512 * 128) return;
    int j  = wid & 7;
    int l  = (wid >> 3) & 63;
    int kt = (wid >> 9) & 7;
    int ct = wid >> 12;                        // 0..15
    int k  = kt * 16 + (l >> 5) * 8 + j;       // 0..127
    int c  = ct * 32 + (l & 31);               // 0..511
    float v;
    if (c < 128)      v = Wg[k * FD + c];                    // Wg1
    else if (c < 256) v = Wg[(128 + k) * FD + (c - 128)];    // Wg2
    else if (c < 384) v = Ws[k * FD + (c - 256)];            // Ws
    else              v = Wr[k * FD + (c - 384)];            // Wr
    Wf[wid] = f2bf(v);
}

// ---------------------------------------------------------------------------
// gemm: [A|B|S|R] = h @ [Wg1|Wg2|Ws|Wr]  (N x 512 output, K = 128)
// A(+bg, bf16), B(bf16), S(+bs, bf16), R -> out(+br, fp32).
// ---------------------------------------------------------------------------
__global__ __launch_bounds__(256) void gemm_kernel(
    const float* __restrict__ h,
    const unsigned short* __restrict__ Wf,
    const float* __restrict__ bg,
    const float* __restrict__ bs,
    const float* __restrict__ br,
    unsigned short* __restrict__ A,
    unsigned short* __restrict__ B,
    unsigned short* __restrict__ S,
    float* __restrict__ out,
    int N)
{
    const int w    = threadIdx.x >> 6;    // 0..3: which weight matrix
    const int lane = threadIdx.x & 63;
    const int rb   = blockIdx.x * 32;

    f32x16 acc[4];
    #pragma unroll
    for (int i = 0; i < 4; ++i)
        #pragma unroll
        for (int r = 0; r < 16; ++r) acc[i][r] = 0.0f;

    int arow = rb + (lane & 31);
    if (arow >= N) arow = N - 1;          // clamp tail rows (dup work, correct out)
    const float* aptr = h + (size_t)arow * FD + (lane >> 5) * 8;

    #pragma unroll
    for (int kt = 0; kt < 8; ++kt) {
        float4 f0 = *(const float4*)(aptr + kt * 16);
        float4 f1 = *(const float4*)(aptr + kt * 16 + 4);
        union { u16x8 u; bf16x8 b; } cv;
        cv.u[0] = f2bf(f0.x); cv.u[1] = f2bf(f0.y);
        cv.u[2] = f2bf(f0.z); cv.u[3] = f2bf(f0.w);
        cv.u[4] = f2bf(f1.x); cv.u[5] = f2bf(f1.y);
        cv.u[6] = f2bf(f1.z); cv.u[7] = f2bf(f1.w);
        bf16x8 a = cv.b;
        #pragma unroll
        for (int i = 0; i < 4; ++i) {
            const unsigned short* bp = Wf + (size_t)(((w * 4 + i) * 8 + kt) * 64 + lane) * 8;
            bf16x8 bfr = *(const bf16x8*)bp;
            acc[i] = __builtin_amdgcn_mfma_f32_32x32x16_bf16(a, bfr, acc[i], 0, 0, 0);
        }
    }

    // C/D layout: col = lane&31, row = (reg&3) + 8*(reg>>2) + 4*(lane>>5)
    const int col_l  = lane & 31;
    const int rhalf  = (lane >> 5) * 4;
    #pragma unroll
    for (int i = 0; i < 4; ++i) {
        int col = i * 32 + col_l;         // 0..127 within this weight matrix
        float bias = (w == 0) ? bg[col] : (w == 2) ? bs[col] : (w == 3) ? br[col] : 0.0f;
        #pragma unroll
        for (int r = 0; r < 16; ++r) {
            int row = rb + (r & 3) + 8 * (r >> 2) + rhalf;
            if (row < N) {
                float v = acc[i][r] + bias;
                size_t off = (size_t)row * FD + col;
                if (w == 0)      A[off] = f2bf(v);    // gate-rec term (+bg folded)
                else if (w == 1) B[off] = f2bf(v);    // gate-send term
                else if (w == 2) S[off] = f2bf(v);    // message content (+bs)
                else             out[off] = v;        // self term h@Wr+br (fp32)
            }
        }
    }
}

// ---------------------------------------------------------------------------
// CSR build: histogram of receivers -> exclusive scan -> scatter send ids.
// idx is int32 [2][E] (harness converts int64 -> int32).
// ---------------------------------------------------------------------------
__global__ __launch_bounds__(256) void hist_kernel(
    const int* __restrict__ idx, int* __restrict__ deg, int E)
{
    int e = blockIdx.x * 256 + threadIdx.x;
    if (e >= E) return;
    atomicAdd(&deg[idx[E + e]], 1);
}

// scan pass 1: per-block sums of deg (1024 elems / block of 256 threads)
__global__ __launch_bounds__(256) void scan1_kernel(
    const int* __restrict__ deg, int* __restrict__ partial, int N)
{
    __shared__ int sh[256];
    int base = blockIdx.x * 1024 + threadIdx.x * 4;
    int s = 0;
    #pragma unroll
    for (int j = 0; j < 4; ++j) s += (base + j < N) ? deg[base + j] : 0;
    sh[threadIdx.x] = s;
    __syncthreads();
    for (int ofs = 128; ofs > 0; ofs >>= 1) {
        if (threadIdx.x < ofs) sh[threadIdx.x] += sh[threadIdx.x + ofs];
        __syncthreads();
    }
    if (threadIdx.x == 0) partial[blockIdx.x] = sh[0];
}

// scan pass 2: single block, exclusive scan of <=256 partials in place
__global__ __launch_bounds__(256) void scan2_kernel(int* __restrict__ partial, int nb)
{
    __shared__ int sh[256];
    int t = threadIdx.x;
    int p = (t < nb) ? partial[t] : 0;
    sh[t] = p;
    __syncthreads();
    for (int ofs = 1; ofs < 256; ofs <<= 1) {
        int x = (t >= ofs) ? sh[t - ofs] : 0;
        __syncthreads();
        sh[t] += x;
        __syncthreads();
    }
    if (t < nb) partial[t] = sh[t] - p;   // exclusive
}

// scan pass 3: recompute local exclusive scan + block offset; IN-PLACE deg->off
__global__ __launch_bounds__(256) void scan3_kernel(
    int* __restrict__ deg, const int* __restrict__ partial, int N)
{
    __shared__ int sh[256];
    int base = blockIdx.x * 1024 + threadIdx.x * 4;
    int v[4];
    #pragma unroll
    for (int j = 0; j < 4; ++j) v[j] = (base + j < N) ? deg[base + j] : 0;
    int tsum = v[0] + v[1] + v[2] + v[3];
    sh[threadIdx.x] = tsum;
    __syncthreads();
    for (int ofs = 1; ofs < 256; ofs <<= 1) {
        int x = (threadIdx.x >= ofs) ? sh[threadIdx.x - ofs] : 0;
        __syncthreads();
        sh[threadIdx.x] += x;
        __syncthreads();
    }
    int run = partial[blockIdx.x] + sh[threadIdx.x] - tsum;  // exclusive at base
    #pragma unroll
    for (int j = 0; j < 4; ++j) {
        if (base + j < N) deg[base + j] = run;
        run += v[j];
    }
}

// scatter: csr[pos] = send, consuming off (after: off[r] = end of segment r;
// start of segment r = (r==0) ? 0 : off[r-1], since consumed off[r-1]=orig off[r])
__global__ __launch_bounds__(256) void scatter_kernel(
    const int* __restrict__ idx, int* __restrict__ off,
    int* __restrict__ csr, int E)
{
    int e = blockIdx.x * 256 + threadIdx.x;
    if (e >= E) return;
    int s = idx[e];
    int r = idx[E + e];
    int pos = atomicAdd(&off[r], 1);
    csr[pos] = s;
}

// ---------------------------------------------------------------------------
// aggregate: one wave per node r; lane handles feature pair (2l, 2l+1).
// out[r] += sum_{s in in(r)} sigmoid(A[r]+B[s]) * S[s].  No atomics.
// ---------------------------------------------------------------------------
__global__ __launch_bounds__(256) void aggregate_kernel(
    const int* __restrict__ off,          // consumed: off[r] = segment end
    const int* __restrict__ csr,
    const unsigned* __restrict__ A,       // bf16x2 per uint, [N][64]
    const unsigned* __restrict__ B,
    const unsigned* __restrict__ S,
    float* __restrict__ out,
    int N)
{
    int r = blockIdx.x * 4 + (threadIdx.x >> 6);
    if (r >= N) return;
    int lane = threadIdx.x & 63;

    int start = (r == 0) ? 0 : off[r - 1];
    int end   = off[r];
    if (start >= end) return;             // deg 0: out already holds R

    unsigned ua = A[(size_t)r * 64 + lane];
    float a0 = bflo(ua), a1 = bfhi(ua);
    float acc0 = 0.0f, acc1 = 0.0f;

    int i = start;
    for (; i + 1 < end; i += 2) {
        int s0 = csr[i], s1 = csr[i + 1];
        unsigned ub0 = B[(size_t)s0 * 64 + lane];
        unsigned us0 = S[(size_t)s0 * 64 + lane];
        unsigned ub1 = B[(size_t)s1 * 64 + lane];
        unsigned us1 = S[(size_t)s1 * 64 + lane];
        float g00 = a0 + bflo(ub0), g01 = a1 + bfhi(ub0);
        float g10 = a0 + bflo(ub1), g11 = a1 + bfhi(ub1);
        acc0 += bflo(us0) / (1.0f + __expf(-g00));
        acc1 += bfhi(us0) / (1.0f + __expf(-g01));
        acc0 += bflo(us1) / (1.0f + __expf(-g10));
        acc1 += bfhi(us1) / (1.0f + __expf(-g11));
    }
    if (i < end) {
        int s0 = csr[i];
        unsigned ub0 = B[(size_t)s0 * 64 + lane];
        unsigned us0 = S[(size_t)s0 * 64 + lane];
        float g00 = a0 + bflo(ub0), g01 = a1 + bfhi(ub0);
        acc0 += bflo(us0) / (1.0f + __expf(-g00));
        acc1 += bfhi(us0) / (1.0f + __expf(-g01));
    }

    float2* o = (float2*)(out + (size_t)r * FD + 2 * lane);
    float2 cur = *o;
    cur.x += acc0;
    cur.y += acc1;
    *o = cur;
}

// ---------------------------------------------------------------------------
extern "C" void kernel_launch(void* const* d_in, const int* in_sizes, int n_in,
                              void* d_out, int out_size, void* d_ws, size_t ws_size,
                              hipStream_t stream)
{
    const float* h  = (const float*)d_in[0];
    const int*   ei = (const int*)d_in[1];      // int32 per harness contract
    const float* Wg = (const float*)d_in[2];
    const float* bg = (const float*)d_in[3];
    const float* Ws = (const float*)d_in[4];
    const float* bs = (const float*)d_in[5];
    const float* Wr = (const float*)d_in[6];
    const float* br = (const float*)d_in[7];
    float* out = (float*)d_out;

    const int N = in_sizes[0] / FD;       // 100000
    const int E = in_sizes[1] / 2;        // 600000

    // Workspace layout:
    //   Wf [512*128 bf16] | A,B,S [N*128 bf16 each] | deg/off [N int] |
    //   partial [256 int] | csr [E int]
    unsigned short* Wf  = (unsigned short*)d_ws;
    unsigned short* Abf = Wf + 512 * FD;
    unsigned short* Bbf = Abf + (size_t)N * FD;
    unsigned short* Sbf = Bbf + (size_t)N * FD;
    int* deg     = (int*)(Sbf + (size_t)N * FD);   // becomes off after scan
    int* partial = deg + N;
    int* csr     = partial + 256;

    size_t need = (size_t)(512 * FD + 3ull * N * FD) * 2 + ((size_t)N + 256 + E) * 4;
    if (ws_size < need) return;   // diagnostic: absmax will equal memset-0 baseline

    const int nb = (N + 1023) / 1024;     // 98 scan blocks (<= 256 required)
    if (nb > 256) return;

    hipMemsetAsync(deg, 0, (size_t)N * 4, stream);

    prep_kernel<<<(512 * FD + 255) / 256, 256, 0, stream>>>(Wg, Ws, Wr, Wf);
    gemm_kernel<<<(N + 31) / 32, 256, 0, stream>>>(h, Wf, bg, bs, br,
                                                   Abf, Bbf, Sbf, out, N);
    hist_kernel<<<(E + 255) / 256, 256, 0, stream>>>(ei, deg, E);
    scan1_kernel<<<nb, 256, 0, stream>>>(deg, partial, N);
    scan2_kernel<<<1, 256, 0, stream>>>(partial, nb);
    scan3_kernel<<<nb, 256, 0, stream>>>(deg, partial, N);
    scatter_kernel<<<(E + 255) / 256, 256, 0, stream>>>(ei, deg, csr, E);
    aggregate_kernel<<<(N + 3) / 4, 256, 0, stream>>>(deg, csr,
                                                      (const unsigned*)Abf,
                                                      (const unsigned*)Bbf,
                                                      (const unsigned*)Sbf,
                                                      out, N);
}